// Round 6
// baseline (648.387 us; speedup 1.0000x reference)
//
#include <hip/hip_runtime.h>
#include <stdint.h>

// GraphAttention on MI355X — ALL I/O float32.
// X[8192][128], A[8192][8192] (0/1), W[4][128][64], a_self[4][64], a_neigh[4][64]
// -> out f32 [8192][256].
//
// KA: A f32 -> bitmask M32[N][256] via wave ballot (268 MB -> 8.4 MB, HBM-bound).
// K0 W->WT bf16 + zero max-keys.  K1 MFMA projection + scores + atomicMax bounds.
// K2 fused mask/exp/softmax-num + P.V MFMA: XpT via global_load_lds double-buffer
//    (0-conflict XOR swizzle), A as L2-hot bitmask dwords in registers,
//    head-per-wave, RB=64, 4 blocks/CU.  K3 combine/divide/relu.

#define NN    8192
#define FF    128
#define FD    64
#define HH    4
#define SPLIT 8
#define KT_PER_SPLIT ((NN / SPLIT) / 32)   // 32 k-tiles of 32 columns per split
#define LOG2E 1.4426950408889634f

typedef __attribute__((ext_vector_type(8))) short short8;
typedef __attribute__((ext_vector_type(4))) float f32x4;

extern "C" __device__ float __ocml_exp2_f32(float);

__device__ __forceinline__ float fast_exp2(float x) {
#if __has_builtin(__builtin_amdgcn_exp2f)
    return __builtin_amdgcn_exp2f(x);
#else
    return __ocml_exp2_f32(x);
#endif
}

__device__ __forceinline__ float bf16_to_f32(unsigned short u) {
    return __builtin_bit_cast(float, ((unsigned)u) << 16);
}
__device__ __forceinline__ unsigned f32_to_bf16_rne(float f) {
    unsigned u = __builtin_bit_cast(unsigned, f);
    u = (u + 0x7FFFu + ((u >> 16) & 1u)) >> 16;
    return u;
}
// Pack two f32 -> two bf16 (truncation) in ONE v_perm_b32.  lo -> bits[15:0].
__device__ __forceinline__ unsigned pack_bf16_trunc(float lo, float hi) {
    return __builtin_amdgcn_perm(__builtin_bit_cast(unsigned, hi),
                                 __builtin_bit_cast(unsigned, lo), 0x07060302u);
}
// async global->LDS DMA, 16B per lane; LDS dest = ldsbase + lane*16.
__device__ __forceinline__ void async_load16(const void* g, void* l) {
    __builtin_amdgcn_global_load_lds(
        (const __attribute__((address_space(1))) unsigned int*)g,
        (__attribute__((address_space(3))) unsigned int*)l, 16, 0, 0);
}
// bit j of v, sign-extended to all 32 bits (0 or 0xFFFFFFFF): v_bfe_i32
__device__ __forceinline__ unsigned bit_mask32(unsigned v, int j) {
#if __has_builtin(__builtin_amdgcn_sbfe)
    return (unsigned)__builtin_amdgcn_sbfe((int)v, j, 1);
#else
    return (unsigned)(-(int)((v >> j) & 1u));
#endif
}
// order-preserving float<->uint keys for atomicMax over signed floats
__device__ __forceinline__ unsigned enc_key(float f) {
    unsigned u = __builtin_bit_cast(unsigned, f);
    return (u & 0x80000000u) ? ~u : (u | 0x80000000u);
}
__device__ __forceinline__ float dec_key(unsigned k) {
    unsigned u = (k & 0x80000000u) ? (k ^ 0x80000000u) : ~k;
    return __builtin_bit_cast(float, u);
}

// ---------------- workspace layout (bytes), ~48 MiB ----------------
#define WS_XPT   0                                   // bf16 [H][64][N]
#define WS_U     (WS_XPT + HH * FD * NN * 2)         // f32  [H][N]  s_self
#define WS_V     (WS_U + HH * NN * 4)                // f32  [H][N]  s_neigh
#define WS_MK    (WS_V + HH * NN * 4)                // u32  [8]: maxU keys, maxV keys
#define WS_WT    (WS_MK + 256)                       // bf16 [H][64][128]
#define WS_ACCP  (WS_WT + HH * FD * FF * 2)          // bf16 [SPLIT][H][N][64]
#define WS_LP    (WS_ACCP + (size_t)SPLIT * HH * NN * FD * 2)  // f32 [SPLIT][H][N]
#define WS_M32   (WS_LP + (size_t)SPLIT * HH * NN * 4)         // u32 [N][256] bitmask

// ---------------- KA: A f32 -> bitmask via wave ballot ----------------
__global__ __launch_bounds__(256) void ka_bitmask(const float* __restrict__ Ag,
                                                  unsigned* __restrict__ M32) {
    const int lane = threadIdx.x & 63;
    const size_t wave_id = (size_t)((blockIdx.x * 256 + threadIdx.x) >> 6);
    const size_t stride = (size_t)8192 * 64;       // 2048 blocks * 4 waves * 64
    size_t base = wave_id * 64;
    #pragma unroll 4
    for (int s = 0; s < 128; ++s) {                // 8192*8192 / stride
        float a = Ag[base + lane];
        unsigned long long m = __ballot(a != 0.0f);
        if (lane == 0)
            *(unsigned long long*)(M32 + (base >> 5)) = m;
        base += stride;
    }
}

// ---------------- K0: W transpose + zero max-keys ----------------
__global__ void k0_transpose_w(const float* __restrict__ W,
                               unsigned short* __restrict__ WT,
                               unsigned* __restrict__ MK) {
    int b = blockIdx.x;            // 32 blocks
    int t = threadIdx.x;
    if (b == 0 && t < 8) MK[t] = 0u;   // key 0 == most-negative float
    int h = b >> 3, fb = b & 7;
    int d = t & 63, fo = t >> 6;
    #pragma unroll
    for (int i = 0; i < 4; ++i) {
        int f = fb * 16 + fo * 4 + i;
        WT[(h * FD + d) * FF + f] = (unsigned short)f32_to_bf16_rne(W[(h * FF + f) * FD + d]);
    }
}

// ---------------- K1: Xp = X @ W[h]; scores; XpT bf16; head max via atomics ----
__global__ __launch_bounds__(256) void k1_project(
        const float* __restrict__ X,               // [N][128] f32
        const unsigned short* __restrict__ WT,     // [H][64][128] bf16
        const float* __restrict__ a_self,          // [H][64] f32
        const float* __restrict__ a_neigh,
        unsigned short* __restrict__ XpT,          // [H][64][N] bf16
        float* __restrict__ U, float* __restrict__ V,
        unsigned* __restrict__ MK) {
    __shared__ __align__(16) char XsB[64 * 272];
    __shared__ __align__(16) char WsB[64 * 272];
    const int rb = blockIdx.x * 64;
    const int h  = blockIdx.y;
    const int t  = threadIdx.x;
    const float4* xs = (const float4*)(X + (size_t)rb * FF);
    #pragma unroll
    for (int i = 0; i < 8; ++i) {
        int c = i * 256 + t;
        float4 v = xs[c];
        uint2 pv;
        pv.x = f32_to_bf16_rne(v.x) | (f32_to_bf16_rne(v.y) << 16);
        pv.y = f32_to_bf16_rne(v.z) | (f32_to_bf16_rne(v.w) << 16);
        *(uint2*)(XsB + (c >> 5) * 272 + (c & 31) * 8) = pv;
    }
    const uint4* wsrc = (const uint4*)(WT + (size_t)h * FD * FF);
    #pragma unroll
    for (int i = 0; i < 4; ++i) {
        int c = i * 256 + t;
        *(uint4*)(WsB + (c >> 4) * 272 + (c & 15) * 16) = wsrc[c];
    }
    __syncthreads();
    const int lane = t & 63, wid = t >> 6;
    const int r15 = lane & 15, quad = lane >> 4;
    const int lrow = wid * 16 + r15;

    f32x4 acc[4];
    #pragma unroll
    for (int cg = 0; cg < 4; ++cg) acc[cg] = (f32x4){0.f, 0.f, 0.f, 0.f};
    #pragma unroll
    for (int kt = 0; kt < 4; ++kt) {
        short8 afr = *(const short8*)(XsB + lrow * 272 + kt * 64 + quad * 16);
        #pragma unroll
        for (int cg = 0; cg < 4; ++cg) {
            short8 bfr = *(const short8*)(WsB + (cg * 16 + r15) * 272 + kt * 64 + quad * 16);
            acc[cg] = __builtin_amdgcn_mfma_f32_16x16x32_bf16(afr, bfr, acc[cg], 0, 0, 0);
        }
    }
    float as[4], an[4];
    #pragma unroll
    for (int cg = 0; cg < 4; ++cg) {
        as[cg] = a_self[h * FD + cg * 16 + r15];
        an[cg] = a_neigh[h * FD + cg * 16 + r15];
    }
    float mu = -1e30f, mv = -1e30f;
    #pragma unroll
    for (int reg = 0; reg < 4; ++reg) {
        float s1 = 0.f, s2 = 0.f;
        #pragma unroll
        for (int cg = 0; cg < 4; ++cg) { s1 += acc[cg][reg] * as[cg]; s2 += acc[cg][reg] * an[cg]; }
        #pragma unroll
        for (int m = 1; m <= 8; m <<= 1) { s1 += __shfl_xor(s1, m); s2 += __shfl_xor(s2, m); }
        mu = fmaxf(mu, s1); mv = fmaxf(mv, s2);
        if (r15 == 0) {
            int n = rb + wid * 16 + quad * 4 + reg;
            U[h * NN + n] = s1;
            V[h * NN + n] = s2;
        }
    }
    mu = fmaxf(mu, __shfl_xor(mu, 16)); mu = fmaxf(mu, __shfl_xor(mu, 32));
    mv = fmaxf(mv, __shfl_xor(mv, 16)); mv = fmaxf(mv, __shfl_xor(mv, 32));
    if (lane == 0) {
        atomicMax(&MK[h], enc_key(mu));
        atomicMax(&MK[4 + h], enc_key(mv));
    }
    #pragma unroll
    for (int cg = 0; cg < 4; ++cg) {
        uint2 val;
        val.x = f32_to_bf16_rne(acc[cg][0]) | (f32_to_bf16_rne(acc[cg][1]) << 16);
        val.y = f32_to_bf16_rne(acc[cg][2]) | (f32_to_bf16_rne(acc[cg][3]) << 16);
        int d = cg * 16 + r15;
        int n0 = rb + wid * 16 + quad * 4;
        *(uint2*)((char*)XpT + ((size_t)(h * FD + d) * NN + n0) * 2) = val;
    }
}

// ---------------- K2: fused scores/softmax-numerator + P.V MFMA ----------------
// 4 waves = 64 rows; wave w owns head w; grid (128 row-blocks, SPLIT m-splits)
// = 1024 blocks = 4/CU.  XpT staged via global_load_lds double-buffer with the
// 0-conflict XOR swizzle (verified r3).  A mask read as L2-hot bitmask dwords,
// register-prefetched one tile ahead.  V read in-loop (L1-hot, 4 KB slice).
__global__ __launch_bounds__(256, 4) void k2_attend(
        const unsigned* __restrict__ M32,          // [N][256] bitmask of A
        const unsigned short* __restrict__ XpT,    // [H][64][N] bf16
        const float* __restrict__ U, const float* __restrict__ V,
        const unsigned* __restrict__ MK,
        unsigned short* __restrict__ accP,         // [SPLIT][H][N][64] bf16
        float* __restrict__ lP) {                  // f32 [SPLIT][H][N]
    __shared__ __align__(16) char Xsb[2][16384];   // 2 x (256 rows x 64B)
    const int t = threadIdx.x;
    const int lane = t & 63, wid = t >> 6;
    const int r15 = lane & 15, quad = lane >> 4;
    const int rb = blockIdx.x * 64;
    const int sp = blockIdx.y;
    const int h = wid;                             // head-per-wave
    const int kb0 = sp * (NN / SPLIT);

    const float M = dec_key(MK[h]) + dec_key(MK[4 + h]);
    const float qoff = -0.8f * M * LOG2E;          // q = 0.2*p + qoff == (0.2 s - M)*log2e
    float u1g[4];
    #pragma unroll
    for (int g = 0; g < 4; ++g)
        u1g[g] = (U[h * NN + rb + g * 16 + r15] - M) * LOG2E;

    f32x4 acc[4][4];
    #pragma unroll
    for (int g = 0; g < 4; ++g)
        #pragma unroll
        for (int cg = 0; cg < 4; ++cg) acc[g][cg] = (f32x4){0.f, 0.f, 0.f, 0.f};
    float lsum[4] = {0.f, 0.f, 0.f, 0.f};

    // XpT DMA: wave w stages head-w rows; instr i covers LDS rows w*64+i*16..+15
    const int srX = wid * 64 + (lane >> 2);
    const int scX = (lane & 3) ^ ((lane >> 3) & 3);
    const char* xsrc = (const char*)XpT + ((size_t)srX * NN + kb0 + scX * 8) * 2;
    const size_t xstep = (size_t)16 * NN * 2;      // +16 source rows per instr
    #pragma unroll
    for (int i = 0; i < 4; ++i)
        async_load16(xsrc + (size_t)i * xstep, &Xsb[0][(wid * 4 + i) * 1024]);

    // mask dwords: lane's row for group g is rb + g*16 + r15; dword sp*32 + kt
    const unsigned* mbase = M32 + (size_t)(rb + r15) * 256 + sp * 32;
    unsigned mg[2][4];
    #pragma unroll
    for (int g = 0; g < 4; ++g) mg[0][g] = mbase[g * 16 * 256];

    const float* vbase = V + h * NN + kb0 + quad * 8;
    const int swzX = (quad ^ ((r15 >> 1) & 3)) * 16;

    #pragma unroll 2
    for (int kt = 0; kt < KT_PER_SPLIT; ++kt) {
        const int cur = kt & 1, nxt = cur ^ 1;
        __syncthreads();                           // drains tile-kt DMA into buf[cur]
        if (kt + 1 < KT_PER_SPLIT) {               // prefetch tile kt+1
            const char* xs2 = xsrc + (size_t)(kt + 1) * 64;   // 32 bf16 cols
            #pragma unroll
            for (int i = 0; i < 4; ++i)
                async_load16(xs2 + (size_t)i * xstep, &Xsb[nxt][(wid * 4 + i) * 1024]);
            #pragma unroll
            for (int g = 0; g < 4; ++g) mg[nxt][g] = mbase[g * 16 * 256 + kt + 1];
        } else {
            #pragma unroll
            for (int g = 0; g < 4; ++g) mg[nxt][g] = mg[cur][g];
        }
        // V for this tile: L1-hot 4 KB slice, in-loop load
        f32x4 va  = *(const f32x4*)(vbase + kt * 32);
        f32x4 vb2 = *(const f32x4*)(vbase + kt * 32 + 4);
        // B-frags for head h (shared across row-groups)
        short8 bfr[4];
        #pragma unroll
        for (int cg = 0; cg < 4; ++cg)
            bfr[cg] = *(const short8*)(&Xsb[cur][(h * FD + cg * 16 + r15) * 64 + swzX]);

        #pragma unroll
        for (int g = 0; g < 4; ++g) {
            const unsigned mbits = mg[cur][g] >> (quad * 8);   // 8 mask bits for this lane
            float w[8];
            #pragma unroll
            for (int j = 0; j < 4; ++j) {
                float p = fmaf(va[j], LOG2E, u1g[g]);
                float q = fmaf(0.2f, p, qoff);
                float e = fast_exp2(fmaxf(p, q));
                w[j] = __builtin_bit_cast(float,
                         __builtin_bit_cast(unsigned, e) & bit_mask32(mbits, j));
            }
            #pragma unroll
            for (int j = 0; j < 4; ++j) {
                float p = fmaf(vb2[j], LOG2E, u1g[g]);
                float q = fmaf(0.2f, p, qoff);
                float e = fast_exp2(fmaxf(p, q));
                w[4 + j] = __builtin_bit_cast(float,
                         __builtin_bit_cast(unsigned, e) & bit_mask32(mbits, 4 + j));
            }
            lsum[g] += ((w[0] + w[1]) + (w[2] + w[3])) + ((w[4] + w[5]) + (w[6] + w[7]));
            uint4 pkv;
            pkv.x = pack_bf16_trunc(w[0], w[1]);
            pkv.y = pack_bf16_trunc(w[2], w[3]);
            pkv.z = pack_bf16_trunc(w[4], w[5]);
            pkv.w = pack_bf16_trunc(w[6], w[7]);
            short8 afrag = __builtin_bit_cast(short8, pkv);
            #pragma unroll
            for (int cg = 0; cg < 4; ++cg)
                acc[g][cg] = __builtin_amdgcn_mfma_f32_16x16x32_bf16(afrag, bfr[cg], acc[g][cg], 0, 0, 0);
        }
    }
    // row denominators: combine the 4 quad-lanes sharing each row
    #pragma unroll
    for (int g = 0; g < 4; ++g) {
        lsum[g] += __shfl_xor(lsum[g], 16);
        lsum[g] += __shfl_xor(lsum[g], 32);
    }
    if (lane < 16) {
        #pragma unroll
        for (int g = 0; g < 4; ++g)
            lP[(size_t)(sp * HH + h) * NN + rb + g * 16 + lane] = lsum[g];
    }
    #pragma unroll
    for (int g = 0; g < 4; ++g)
        #pragma unroll
        for (int cg = 0; cg < 4; ++cg) {
            int d = cg * 16 + r15;
            #pragma unroll
            for (int reg = 0; reg < 4; ++reg) {
                int n = rb + g * 16 + quad * 4 + reg;
                accP[((size_t)(sp * HH + h) * NN + n) * FD + d] =
                    (unsigned short)f32_to_bf16_rne(acc[g][cg][reg]);
            }
        }
}

// ---------------- K3: combine splits, divide, relu, concat ----------------
__global__ void k3_combine(const unsigned short* __restrict__ accP,
                           const float* __restrict__ lP,
                           float* __restrict__ out) {
    int e = blockIdx.x * 256 + threadIdx.x;     // 2M elements: out[n][h*64+d]
    int n = e >> 8, c = e & 255;
    int h = c >> 6, d = c & 63;
    float num = 0.f, den = 0.f;
    #pragma unroll
    for (int s = 0; s < SPLIT; ++s) {
        num += bf16_to_f32(accP[((size_t)(s * HH + h) * NN + n) * FD + d]);
        den += lP[(size_t)(s * HH + h) * NN + n];
    }
    out[e] = fmaxf(num * __builtin_amdgcn_rcpf(den), 0.f);
}

extern "C" void kernel_launch(void* const* d_in, const int* in_sizes, int n_in,
                              void* d_out, int out_size, void* d_ws, size_t ws_size,
                              hipStream_t stream) {
    (void)in_sizes; (void)n_in; (void)out_size; (void)ws_size;
    const float* X       = (const float*)d_in[0];
    const float* A       = (const float*)d_in[1];
    const float* W       = (const float*)d_in[2];
    const float* a_self  = (const float*)d_in[3];
    const float* a_neigh = (const float*)d_in[4];
    char* ws = (char*)d_ws;
    unsigned short* XpT  = (unsigned short*)(ws + WS_XPT);
    float*          U    = (float*)(ws + WS_U);
    float*          V    = (float*)(ws + WS_V);
    unsigned*       MK   = (unsigned*)(ws + WS_MK);
    unsigned short* WT   = (unsigned short*)(ws + WS_WT);
    unsigned short* accP = (unsigned short*)(ws + WS_ACCP);
    float*          lP   = (float*)(ws + WS_LP);
    unsigned*       M32  = (unsigned*)(ws + WS_M32);
    float*          out  = (float*)d_out;

    ka_bitmask<<<dim3(2048), dim3(256), 0, stream>>>(A, M32);
    k0_transpose_w<<<dim3(32), dim3(256), 0, stream>>>(W, WT, MK);
    k1_project<<<dim3(NN / 64, HH), dim3(256), 0, stream>>>(X, WT, a_self, a_neigh, XpT, U, V, MK);
    k2_attend<<<dim3(NN / 64, SPLIT), dim3(256), 0, stream>>>(M32, XpT, U, V, MK, accP, lP);
    k3_combine<<<dim3(NN), dim3(256), 0, stream>>>(accP, lP, out);
}

// Round 7
// 538.010 us; speedup vs baseline: 1.2052x; 1.2052x over previous
//
#include <hip/hip_runtime.h>
#include <stdint.h>

// GraphAttention on MI355X — ALL I/O float32.
// X[8192][128], A[8192][8192] (0/1), W[4][128][64], a_self[4][64], a_neigh[4][64]
// -> out f32 [8192][256].
//
// KA: A f32 -> bitmask M32[N][256] via wave ballot (268 MB -> 8.4 MB, HBM-bound).
// K0 W->WT bf16 + zero max-keys.  K1 MFMA projection + scores + atomicMax bounds.
// K2 fused mask/exp/softmax-num + P.V MFMA: XpT via global_load_lds double-buffer
//    (0-conflict XOR swizzle); block's 8 KB mask slice staged in LDS once
//    (stride-33 pad -> conflict-free ds_read); head-per-wave; RB=64; 3 blocks/CU.
// K3 combine/divide/relu.

#define NN    8192
#define FF    128
#define FD    64
#define HH    4
#define SPLIT 8
#define KT_PER_SPLIT ((NN / SPLIT) / 32)   // 32 k-tiles of 32 columns per split
#define LOG2E 1.4426950408889634f

typedef __attribute__((ext_vector_type(8))) short short8;
typedef __attribute__((ext_vector_type(4))) float f32x4;

extern "C" __device__ float __ocml_exp2_f32(float);

__device__ __forceinline__ float fast_exp2(float x) {
#if __has_builtin(__builtin_amdgcn_exp2f)
    return __builtin_amdgcn_exp2f(x);
#else
    return __ocml_exp2_f32(x);
#endif
}

__device__ __forceinline__ float bf16_to_f32(unsigned short u) {
    return __builtin_bit_cast(float, ((unsigned)u) << 16);
}
__device__ __forceinline__ unsigned f32_to_bf16_rne(float f) {
    unsigned u = __builtin_bit_cast(unsigned, f);
    u = (u + 0x7FFFu + ((u >> 16) & 1u)) >> 16;
    return u;
}
// Pack two f32 -> two bf16 (truncation) in ONE v_perm_b32.  lo -> bits[15:0].
__device__ __forceinline__ unsigned pack_bf16_trunc(float lo, float hi) {
    return __builtin_amdgcn_perm(__builtin_bit_cast(unsigned, hi),
                                 __builtin_bit_cast(unsigned, lo), 0x07060302u);
}
// async global->LDS DMA, 16B per lane; LDS dest = ldsbase + lane*16.
__device__ __forceinline__ void async_load16(const void* g, void* l) {
    __builtin_amdgcn_global_load_lds(
        (const __attribute__((address_space(1))) unsigned int*)g,
        (__attribute__((address_space(3))) unsigned int*)l, 16, 0, 0);
}
// bit j of v, sign-extended to all 32 bits (0 or 0xFFFFFFFF): v_bfe_i32
__device__ __forceinline__ unsigned bit_mask32(unsigned v, int j) {
#if __has_builtin(__builtin_amdgcn_sbfe)
    return (unsigned)__builtin_amdgcn_sbfe((int)v, j, 1);
#else
    return (unsigned)(-(int)((v >> j) & 1u));
#endif
}
// order-preserving float<->uint keys for atomicMax over signed floats
__device__ __forceinline__ unsigned enc_key(float f) {
    unsigned u = __builtin_bit_cast(unsigned, f);
    return (u & 0x80000000u) ? ~u : (u | 0x80000000u);
}
__device__ __forceinline__ float dec_key(unsigned k) {
    unsigned u = (k & 0x80000000u) ? (k ^ 0x80000000u) : ~k;
    return __builtin_bit_cast(float, u);
}

// ---------------- workspace layout (bytes), ~48 MiB ----------------
#define WS_XPT   0                                   // bf16 [H][64][N]
#define WS_U     (WS_XPT + HH * FD * NN * 2)         // f32  [H][N]  s_self
#define WS_V     (WS_U + HH * NN * 4)                // f32  [H][N]  s_neigh
#define WS_MK    (WS_V + HH * NN * 4)                // u32  [8]: maxU keys, maxV keys
#define WS_WT    (WS_MK + 256)                       // bf16 [H][64][128]
#define WS_ACCP  (WS_WT + HH * FD * FF * 2)          // bf16 [SPLIT][H][N][64]
#define WS_LP    (WS_ACCP + (size_t)SPLIT * HH * NN * FD * 2)  // f32 [SPLIT][H][N]
#define WS_M32   (WS_LP + (size_t)SPLIT * HH * NN * 4)         // u32 [N][256] bitmask

// ---------------- KA: A f32 -> bitmask via wave ballot ----------------
__global__ __launch_bounds__(256) void ka_bitmask(const float* __restrict__ Ag,
                                                  unsigned* __restrict__ M32) {
    const int lane = threadIdx.x & 63;
    const size_t wave_id = (size_t)((blockIdx.x * 256 + threadIdx.x) >> 6);
    const size_t stride = (size_t)8192 * 64;       // 2048 blocks * 4 waves * 64
    size_t base = wave_id * 64;
    #pragma unroll 4
    for (int s = 0; s < 128; ++s) {                // 8192*8192 / stride
        float a = Ag[base + lane];
        unsigned long long m = __ballot(a != 0.0f);
        if (lane == 0)
            *(unsigned long long*)(M32 + (base >> 5)) = m;
        base += stride;
    }
}

// ---------------- K0: W transpose + zero max-keys ----------------
__global__ void k0_transpose_w(const float* __restrict__ W,
                               unsigned short* __restrict__ WT,
                               unsigned* __restrict__ MK) {
    int b = blockIdx.x;            // 32 blocks
    int t = threadIdx.x;
    if (b == 0 && t < 8) MK[t] = 0u;   // key 0 == most-negative float
    int h = b >> 3, fb = b & 7;
    int d = t & 63, fo = t >> 6;
    #pragma unroll
    for (int i = 0; i < 4; ++i) {
        int f = fb * 16 + fo * 4 + i;
        WT[(h * FD + d) * FF + f] = (unsigned short)f32_to_bf16_rne(W[(h * FF + f) * FD + d]);
    }
}

// ---------------- K1: Xp = X @ W[h]; scores; XpT bf16; head max via atomics ----
__global__ __launch_bounds__(256) void k1_project(
        const float* __restrict__ X,               // [N][128] f32
        const unsigned short* __restrict__ WT,     // [H][64][128] bf16
        const float* __restrict__ a_self,          // [H][64] f32
        const float* __restrict__ a_neigh,
        unsigned short* __restrict__ XpT,          // [H][64][N] bf16
        float* __restrict__ U, float* __restrict__ V,
        unsigned* __restrict__ MK) {
    __shared__ __align__(16) char XsB[64 * 272];
    __shared__ __align__(16) char WsB[64 * 272];
    const int rb = blockIdx.x * 64;
    const int h  = blockIdx.y;
    const int t  = threadIdx.x;
    const float4* xs = (const float4*)(X + (size_t)rb * FF);
    #pragma unroll
    for (int i = 0; i < 8; ++i) {
        int c = i * 256 + t;
        float4 v = xs[c];
        uint2 pv;
        pv.x = f32_to_bf16_rne(v.x) | (f32_to_bf16_rne(v.y) << 16);
        pv.y = f32_to_bf16_rne(v.z) | (f32_to_bf16_rne(v.w) << 16);
        *(uint2*)(XsB + (c >> 5) * 272 + (c & 31) * 8) = pv;
    }
    const uint4* wsrc = (const uint4*)(WT + (size_t)h * FD * FF);
    #pragma unroll
    for (int i = 0; i < 4; ++i) {
        int c = i * 256 + t;
        *(uint4*)(WsB + (c >> 4) * 272 + (c & 15) * 16) = wsrc[c];
    }
    __syncthreads();
    const int lane = t & 63, wid = t >> 6;
    const int r15 = lane & 15, quad = lane >> 4;
    const int lrow = wid * 16 + r15;

    f32x4 acc[4];
    #pragma unroll
    for (int cg = 0; cg < 4; ++cg) acc[cg] = (f32x4){0.f, 0.f, 0.f, 0.f};
    #pragma unroll
    for (int kt = 0; kt < 4; ++kt) {
        short8 afr = *(const short8*)(XsB + lrow * 272 + kt * 64 + quad * 16);
        #pragma unroll
        for (int cg = 0; cg < 4; ++cg) {
            short8 bfr = *(const short8*)(WsB + (cg * 16 + r15) * 272 + kt * 64 + quad * 16);
            acc[cg] = __builtin_amdgcn_mfma_f32_16x16x32_bf16(afr, bfr, acc[cg], 0, 0, 0);
        }
    }
    float as[4], an[4];
    #pragma unroll
    for (int cg = 0; cg < 4; ++cg) {
        as[cg] = a_self[h * FD + cg * 16 + r15];
        an[cg] = a_neigh[h * FD + cg * 16 + r15];
    }
    float mu = -1e30f, mv = -1e30f;
    #pragma unroll
    for (int reg = 0; reg < 4; ++reg) {
        float s1 = 0.f, s2 = 0.f;
        #pragma unroll
        for (int cg = 0; cg < 4; ++cg) { s1 += acc[cg][reg] * as[cg]; s2 += acc[cg][reg] * an[cg]; }
        #pragma unroll
        for (int m = 1; m <= 8; m <<= 1) { s1 += __shfl_xor(s1, m); s2 += __shfl_xor(s2, m); }
        mu = fmaxf(mu, s1); mv = fmaxf(mv, s2);
        if (r15 == 0) {
            int n = rb + wid * 16 + quad * 4 + reg;
            U[h * NN + n] = s1;
            V[h * NN + n] = s2;
        }
    }
    mu = fmaxf(mu, __shfl_xor(mu, 16)); mu = fmaxf(mu, __shfl_xor(mu, 32));
    mv = fmaxf(mv, __shfl_xor(mv, 16)); mv = fmaxf(mv, __shfl_xor(mv, 32));
    if (lane == 0) {
        atomicMax(&MK[h], enc_key(mu));
        atomicMax(&MK[4 + h], enc_key(mv));
    }
    #pragma unroll
    for (int cg = 0; cg < 4; ++cg) {
        uint2 val;
        val.x = f32_to_bf16_rne(acc[cg][0]) | (f32_to_bf16_rne(acc[cg][1]) << 16);
        val.y = f32_to_bf16_rne(acc[cg][2]) | (f32_to_bf16_rne(acc[cg][3]) << 16);
        int d = cg * 16 + r15;
        int n0 = rb + wid * 16 + quad * 4;
        *(uint2*)((char*)XpT + ((size_t)(h * FD + d) * NN + n0) * 2) = val;
    }
}

// ---------------- K2: fused scores/softmax-numerator + P.V MFMA ----------------
// 4 waves = 64 rows; wave w owns head w; grid (128 row-blocks, SPLIT m-splits).
// XpT staged via global_load_lds double-buffer (0-conflict XOR swizzle).
// Block's mask slice (64 rows x 32 tile-dwords, 8 KB) staged in LDS ONCE with
// stride-33 pad: in-loop ds_read banks = (r15*33+kt)%32 = (r15+kt)%32, distinct
// per r15 -> conflict-free broadcast.  V rows L1-hot, loaded in-loop.
__global__ __launch_bounds__(256, 3) void k2_attend(
        const unsigned* __restrict__ M32,          // [N][256] bitmask of A
        const unsigned short* __restrict__ XpT,    // [H][64][N] bf16
        const float* __restrict__ U, const float* __restrict__ V,
        const unsigned* __restrict__ MK,
        unsigned short* __restrict__ accP,         // [SPLIT][H][N][64] bf16
        float* __restrict__ lP) {                  // f32 [SPLIT][H][N]
    __shared__ __align__(16) char Xsb[2][16384];   // 2 x (256 rows x 64B)
    __shared__ unsigned Msl[64 * 33];              // mask slice, stride-33 pad
    const int t = threadIdx.x;
    const int lane = t & 63, wid = t >> 6;
    const int r15 = lane & 15, quad = lane >> 4;
    const int rb = blockIdx.x * 64;
    const int sp = blockIdx.y;
    const int h = wid;                             // head-per-wave
    const int kb0 = sp * (NN / SPLIT);

    // stage mask slice: row t>>2, dwords (t&3)*8..+7 (32B per thread, coalesced)
    {
        const int row = t >> 2, c0 = (t & 3) * 8;
        const uint4* msrc = (const uint4*)(M32 + (size_t)(rb + row) * 256 + sp * 32 + c0);
        uint4 m0 = msrc[0], m1 = msrc[1];
        unsigned* mdst = &Msl[row * 33 + c0];
        mdst[0] = m0.x; mdst[1] = m0.y; mdst[2] = m0.z; mdst[3] = m0.w;
        mdst[4] = m1.x; mdst[5] = m1.y; mdst[6] = m1.z; mdst[7] = m1.w;
    }

    const float M = dec_key(MK[h]) + dec_key(MK[4 + h]);
    const float qoff = -0.8f * M * LOG2E;          // q = 0.2*p + qoff == (0.2 s - M)*log2e
    float u1g[4];
    #pragma unroll
    for (int g = 0; g < 4; ++g)
        u1g[g] = (U[h * NN + rb + g * 16 + r15] - M) * LOG2E;

    f32x4 acc[4][4];
    #pragma unroll
    for (int g = 0; g < 4; ++g)
        #pragma unroll
        for (int cg = 0; cg < 4; ++cg) acc[g][cg] = (f32x4){0.f, 0.f, 0.f, 0.f};
    float lsum[4] = {0.f, 0.f, 0.f, 0.f};

    // XpT DMA: wave w stages head-w rows; instr i covers LDS rows w*64+i*16..+15
    const int srX = wid * 64 + (lane >> 2);
    const int scX = (lane & 3) ^ ((lane >> 3) & 3);
    const char* xsrc = (const char*)XpT + ((size_t)srX * NN + kb0 + scX * 8) * 2;
    const size_t xstep = (size_t)16 * NN * 2;      // +16 source rows per instr
    #pragma unroll
    for (int i = 0; i < 4; ++i)
        async_load16(xsrc + (size_t)i * xstep, &Xsb[0][(wid * 4 + i) * 1024]);

    const float* vbase = V + h * NN + kb0 + quad * 8;
    const int swzX = (quad ^ ((r15 >> 1) & 3)) * 16;

    #pragma unroll 2
    for (int kt = 0; kt < KT_PER_SPLIT; ++kt) {
        const int cur = kt & 1, nxt = cur ^ 1;
        __syncthreads();                           // drains tile-kt DMA (and Msl stage)
        if (kt + 1 < KT_PER_SPLIT) {               // prefetch tile kt+1
            const char* xs2 = xsrc + (size_t)(kt + 1) * 64;   // 32 bf16 cols
            #pragma unroll
            for (int i = 0; i < 4; ++i)
                async_load16(xs2 + (size_t)i * xstep, &Xsb[nxt][(wid * 4 + i) * 1024]);
        }
        // V for this tile: L1-hot 4 KB slice, in-loop load (quad-broadcast)
        f32x4 va  = *(const f32x4*)(vbase + kt * 32);
        f32x4 vb2 = *(const f32x4*)(vbase + kt * 32 + 4);
        // B-frags for head h (shared across row-groups)
        short8 bfr[4];
        #pragma unroll
        for (int cg = 0; cg < 4; ++cg)
            bfr[cg] = *(const short8*)(&Xsb[cur][(h * FD + cg * 16 + r15) * 64 + swzX]);

        #pragma unroll
        for (int g = 0; g < 4; ++g) {
            const unsigned mbits = Msl[(g * 16 + r15) * 33 + kt] >> (quad * 8);
            float w[8];
            #pragma unroll
            for (int j = 0; j < 4; ++j) {
                float p = fmaf(va[j], LOG2E, u1g[g]);
                float q = fmaf(0.2f, p, qoff);
                float e = fast_exp2(fmaxf(p, q));
                w[j] = __builtin_bit_cast(float,
                         __builtin_bit_cast(unsigned, e) & bit_mask32(mbits, j));
            }
            #pragma unroll
            for (int j = 0; j < 4; ++j) {
                float p = fmaf(vb2[j], LOG2E, u1g[g]);
                float q = fmaf(0.2f, p, qoff);
                float e = fast_exp2(fmaxf(p, q));
                w[4 + j] = __builtin_bit_cast(float,
                         __builtin_bit_cast(unsigned, e) & bit_mask32(mbits, 4 + j));
            }
            lsum[g] += ((w[0] + w[1]) + (w[2] + w[3])) + ((w[4] + w[5]) + (w[6] + w[7]));
            uint4 pkv;
            pkv.x = pack_bf16_trunc(w[0], w[1]);
            pkv.y = pack_bf16_trunc(w[2], w[3]);
            pkv.z = pack_bf16_trunc(w[4], w[5]);
            pkv.w = pack_bf16_trunc(w[6], w[7]);
            short8 afrag = __builtin_bit_cast(short8, pkv);
            #pragma unroll
            for (int cg = 0; cg < 4; ++cg)
                acc[g][cg] = __builtin_amdgcn_mfma_f32_16x16x32_bf16(afrag, bfr[cg], acc[g][cg], 0, 0, 0);
        }
    }
    // row denominators: combine the 4 quad-lanes sharing each row
    #pragma unroll
    for (int g = 0; g < 4; ++g) {
        lsum[g] += __shfl_xor(lsum[g], 16);
        lsum[g] += __shfl_xor(lsum[g], 32);
    }
    if (lane < 16) {
        #pragma unroll
        for (int g = 0; g < 4; ++g)
            lP[(size_t)(sp * HH + h) * NN + rb + g * 16 + lane] = lsum[g];
    }
    #pragma unroll
    for (int g = 0; g < 4; ++g)
        #pragma unroll
        for (int cg = 0; cg < 4; ++cg) {
            int d = cg * 16 + r15;
            #pragma unroll
            for (int reg = 0; reg < 4; ++reg) {
                int n = rb + g * 16 + quad * 4 + reg;
                accP[((size_t)(sp * HH + h) * NN + n) * FD + d] =
                    (unsigned short)f32_to_bf16_rne(acc[g][cg][reg]);
            }
        }
}

// ---------------- K3: combine splits, divide, relu, concat ----------------
__global__ void k3_combine(const unsigned short* __restrict__ accP,
                           const float* __restrict__ lP,
                           float* __restrict__ out) {
    int e = blockIdx.x * 256 + threadIdx.x;     // 2M elements: out[n][h*64+d]
    int n = e >> 8, c = e & 255;
    int h = c >> 6, d = c & 63;
    float num = 0.f, den = 0.f;
    #pragma unroll
    for (int s = 0; s < SPLIT; ++s) {
        num += bf16_to_f32(accP[((size_t)(s * HH + h) * NN + n) * FD + d]);
        den += lP[(size_t)(s * HH + h) * NN + n];
    }
    out[e] = fmaxf(num * __builtin_amdgcn_rcpf(den), 0.f);
}

extern "C" void kernel_launch(void* const* d_in, const int* in_sizes, int n_in,
                              void* d_out, int out_size, void* d_ws, size_t ws_size,
                              hipStream_t stream) {
    (void)in_sizes; (void)n_in; (void)out_size; (void)ws_size;
    const float* X       = (const float*)d_in[0];
    const float* A       = (const float*)d_in[1];
    const float* W       = (const float*)d_in[2];
    const float* a_self  = (const float*)d_in[3];
    const float* a_neigh = (const float*)d_in[4];
    char* ws = (char*)d_ws;
    unsigned short* XpT  = (unsigned short*)(ws + WS_XPT);
    float*          U    = (float*)(ws + WS_U);
    float*          V    = (float*)(ws + WS_V);
    unsigned*       MK   = (unsigned*)(ws + WS_MK);
    unsigned short* WT   = (unsigned short*)(ws + WS_WT);
    unsigned short* accP = (unsigned short*)(ws + WS_ACCP);
    float*          lP   = (float*)(ws + WS_LP);
    unsigned*       M32  = (unsigned*)(ws + WS_M32);
    float*          out  = (float*)d_out;

    ka_bitmask<<<dim3(2048), dim3(256), 0, stream>>>(A, M32);
    k0_transpose_w<<<dim3(32), dim3(256), 0, stream>>>(W, WT, MK);
    k1_project<<<dim3(NN / 64, HH), dim3(256), 0, stream>>>(X, WT, a_self, a_neigh, XpT, U, V, MK);
    k2_attend<<<dim3(NN / 64, SPLIT), dim3(256), 0, stream>>>(M32, XpT, U, V, MK, accP, lP);
    k3_combine<<<dim3(NN), dim3(256), 0, stream>>>(accP, lP, out);
}